// Round 12
// baseline (194.395 us; speedup 1.0000x reference)
//
#include <hip/hip_runtime.h>
#include <hip/hip_bf16.h>

#define N_NODES 50000
#define N_EDGES 800000
#define N_REL 8
#define N_BASES 16
#define D 128
#define NCB 196                    // coarse buckets of 256 dsts
#define NSEG (N_NODES * N_REL)     // 400000
#define NFB 1563                   // fused blocks: ceil(50000/32)
#define ACHUNK 2048

typedef __attribute__((ext_vector_type(8))) short bf16x8;
typedef __attribute__((ext_vector_type(4))) float f32x4;

__device__ inline unsigned short f2bf(float f) {
    unsigned int x = __float_as_uint(f);
    unsigned int r = x + 0x7FFFu + ((x >> 16) & 1u);
    return (unsigned short)(r >> 16);
}
__device__ inline unsigned int cvtpk(float lo, float hi) {
    unsigned int r;
    asm("v_cvt_pk_bf16_f32 %0, %1, %2" : "=v"(r) : "v"(lo), "v"(hi));
    return r;
}

// ---------------------------------------------------------------------------
// K1: fused {histA (blocks 0..781), cvtx (782..3906), makeW (3907..3978)}
#define K1_HIST 782
#define K1_CVT  3125
#define K1_MKW  72
__global__ __launch_bounds__(256) void k_setup1(const float* __restrict__ x,
                                                const float* __restrict__ coeff,
                                                const float* __restrict__ bases,
                                                const float* __restrict__ self_loop,
                                                const int* __restrict__ ei,
                                                unsigned short* __restrict__ xb,
                                                unsigned short* __restrict__ WbT,
                                                int* __restrict__ ccnt) {
    __shared__ int h[256];
    __shared__ unsigned short tile[128][17];
    const int b = blockIdx.x;
    const int t = threadIdx.x;

    if (b < K1_HIST) {
        h[t] = 0;
        __syncthreads();
        int idx = b * 1024 + t * 4;
        if (idx < N_EDGES) {
            int4 d = *(const int4*)&ei[N_EDGES + idx];
            atomicAdd(&h[d.x >> 8], 1);
            atomicAdd(&h[d.y >> 8], 1);
            atomicAdd(&h[d.z >> 8], 1);
            atomicAdd(&h[d.w >> 8], 1);
        }
        __syncthreads();
        if (t < NCB && h[t]) atomicAdd(&ccnt[t], h[t]);
    } else if (b < K1_HIST + K1_CVT) {
        int i = (b - K1_HIST) * 256 + t;
        const float4* xp = (const float4*)x;
        float4 a = xp[i * 2], bb = xp[i * 2 + 1];
        int4 o;
        o.x = (int)f2bf(a.x) | ((int)f2bf(a.y) << 16);
        o.y = (int)f2bf(a.z) | ((int)f2bf(a.w) << 16);
        o.z = (int)f2bf(bb.x) | ((int)f2bf(bb.y) << 16);
        o.w = (int)f2bf(bb.z) | ((int)f2bf(bb.w) << 16);
        ((int4*)xb)[i] = o;
    } else {
        int local = b - K1_HIST - K1_CVT;
        const int r = local >> 3, os = local & 7;
        const int i = t >> 1, ob = (t & 1) * 8;
        const int gcol = os * 16 + ob;
        float s[8];
        if (r < 8) {
            float c[16];
#pragma unroll
            for (int bb = 0; bb < 16; ++bb) c[bb] = coeff[r * 16 + bb];
#pragma unroll
            for (int j = 0; j < 8; ++j) s[j] = 0.f;
#pragma unroll
            for (int bb = 0; bb < 16; ++bb) {
                const float* bp = bases + bb * 16384 + i * 128 + gcol;
                float4 v0 = *(const float4*)bp;
                float4 v1 = *(const float4*)(bp + 4);
                s[0] += c[bb] * v0.x; s[1] += c[bb] * v0.y; s[2] += c[bb] * v0.z; s[3] += c[bb] * v0.w;
                s[4] += c[bb] * v1.x; s[5] += c[bb] * v1.y; s[6] += c[bb] * v1.z; s[7] += c[bb] * v1.w;
            }
        } else {
            const float* sp = self_loop + i * 128 + gcol;
            float4 v0 = *(const float4*)sp;
            float4 v1 = *(const float4*)(sp + 4);
            s[0] = v0.x; s[1] = v0.y; s[2] = v0.z; s[3] = v0.w;
            s[4] = v1.x; s[5] = v1.y; s[6] = v1.z; s[7] = v1.w;
        }
#pragma unroll
        for (int j = 0; j < 8; ++j) tile[i][ob + j] = f2bf(s[j]);
        __syncthreads();
        const int o = t >> 4, ic = (t & 15) << 3;
        unsigned int pk[4];
#pragma unroll
        for (int j = 0; j < 4; ++j)
            pk[j] = (unsigned int)tile[ic + j * 2][o] | ((unsigned int)tile[ic + j * 2 + 1][o] << 16);
        *(int4*)&WbT[(size_t)r * 16384 + (os * 16 + o) * 128 + ic] = *(int4*)pk;
    }
}

// ---------------------------------------------------------------------------
// exclusive scan of ccnt[196] -> coff[197], gcur; pad roff2 tail with total
__global__ __launch_bounds__(256) void k_scanA1(const int* __restrict__ ccnt,
                                                int* __restrict__ coff,
                                                int* __restrict__ gcur,
                                                int* __restrict__ roff2) {
    int t = threadIdx.x;
    int v = (t < NCB) ? ccnt[t] : 0;
    int lane = t & 63, wv = t >> 6;
    int inc = v;
#pragma unroll
    for (int off = 1; off < 64; off <<= 1) {
        int y = __shfl_up(inc, off);
        if (lane >= off) inc += y;
    }
    __shared__ int ws4[4];
    __shared__ int tot;
    if (lane == 63) ws4[wv] = inc;
    __syncthreads();
    int wb = 0;
    for (int i = 0; i < wv; ++i) wb += ws4[i];
    int ex = wb + inc - v;
    if (t < NCB) { coff[t] = ex; gcur[t] = ex; }
    if (t == NCB - 1) { coff[NCB] = ex + v; tot = ex + v; }
    __syncthreads();
    for (int i = t; i < 192; i += 256) roff2[NSEG + i] = tot;
}

// ---------------------------------------------------------------------------
// bucket edges into coarse segments; rec = src | rel<<16 | (dst&255)<<19
__global__ __launch_bounds__(256) void k_bucketA(const int* __restrict__ ei,
                                                 const int* __restrict__ et,
                                                 int* __restrict__ gcur,
                                                 unsigned int* __restrict__ recA) {
    __shared__ int lcnt[NCB], lbase[NCB];
    const int base = blockIdx.x * ACHUNK;
    const int t = threadIdx.x;
    if (t < NCB) lcnt[t] = 0;
    __syncthreads();
    unsigned int rec[8];
    int mb[8];
#pragma unroll
    for (int i = 0; i < 8; ++i) {
        int e = base + t + i * 256;
        if (e < N_EDGES) {
            int src = ei[e];
            int dst = ei[N_EDGES + e];
            int r = et[e];
            rec[i] = (unsigned)src | ((unsigned)r << 16) | ((unsigned)(dst & 255) << 19);
            mb[i] = dst >> 8;
            atomicAdd(&lcnt[mb[i]], 1);
        } else mb[i] = -1;
    }
    __syncthreads();
    if (t < NCB) lbase[t] = lcnt[t] ? atomicAdd(&gcur[t], lcnt[t]) : 0;
    __syncthreads();
    if (t < NCB) lcnt[t] = 0;
    __syncthreads();
#pragma unroll
    for (int i = 0; i < 8; ++i) {
        if (mb[i] < 0) continue;
        int pos = lbase[mb[i]] + atomicAdd(&lcnt[mb[i]], 1);
        recA[pos] = rec[i];
    }
}

// ---------------------------------------------------------------------------
// per coarse bucket: (dst,rel)-sorted csr16 + roff2 (all LDS atomics)
__global__ __launch_bounds__(256) void k_buildC(const unsigned int* __restrict__ recA,
                                                const int* __restrict__ coff,
                                                int* __restrict__ roff2,
                                                unsigned short* __restrict__ csr16) {
    const int b = blockIdx.x, t = threadIdx.x;
    const int s0 = coff[b], s1 = coff[b + 1];
    __shared__ int h2[2048];    // (dst&255)*8 + rel
    __shared__ int cur2[2048];
    __shared__ int ws4[4];
    for (int i = t; i < 2048; i += 256) h2[i] = 0;
    __syncthreads();
    for (int i = s0 + t; i < s1; i += 256) {
        unsigned int p = recA[i];
        atomicAdd(&h2[((p >> 19) & 255) * 8 + ((p >> 16) & 7)], 1);
    }
    __syncthreads();
    int pre[8], sum = 0;
#pragma unroll
    for (int j = 0; j < 8; ++j) { pre[j] = sum; sum += h2[t * 8 + j]; }
    int lane = t & 63, wv = t >> 6;
    int inc = sum;
#pragma unroll
    for (int off = 1; off < 64; off <<= 1) {
        int y = __shfl_up(inc, off);
        if (lane >= off) inc += y;
    }
    if (lane == 63) ws4[wv] = inc;
    __syncthreads();
    int wb = 0;
    for (int i = 0; i < wv; ++i) wb += ws4[i];
    int ex = wb + inc - sum;
    int dst = (b << 8) + t;
#pragma unroll
    for (int j = 0; j < 8; ++j) cur2[t * 8 + j] = ex + pre[j];
    if (dst < N_NODES) {
#pragma unroll
        for (int j = 0; j < 8; ++j) roff2[dst * 8 + j] = s0 + ex + pre[j];
    }
    __syncthreads();
    for (int i = s0 + t; i < s1; i += 256) {
        unsigned int p = recA[i];
        int idx2 = ((p >> 19) & 255) * 8 + ((p >> 16) & 7);
        int pos = s0 + atomicAdd(&cur2[idx2], 1);
        csr16[pos] = (unsigned short)(p & 0xFFFF);
    }
}

// ---------------------------------------------------------------------------
// FUSED v4: 32 dsts/block, 8 waves. Phase 1 = gather2-style wave-per-dst:
// wave owns 4 dsts; per edge the WHOLE wave loads one 256B xb row (4B/lane),
// 8 edges batched in flight; rel is wave-uniform (readfirstlane + switch into
// named float2 accumulators). dinv at pack, bf16 into swizzled agg LDS.
// Phase 2 = fused3's verified 9-panel MFMA -> fp32 out.
__global__ __launch_bounds__(512) void k_fused4(const unsigned short* __restrict__ xb,
                                                const unsigned short* __restrict__ WbT,
                                                const unsigned short* __restrict__ csr16,
                                                const int* __restrict__ roff2,
                                                float* __restrict__ out) {
    __shared__ __attribute__((aligned(16))) unsigned short agg[32 * 1024];  // 64 KB
    __shared__ int roff_s[257];
    __shared__ unsigned int sE32[8][64];
    const int g = blockIdx.x, g32 = g * 32, t = threadIdx.x;
    const int wv = t >> 6, lane = t & 63;

    if (t < 257) roff_s[t] = roff2[g * 256 + t];
    __syncthreads();

    // ---- phase 1: wave-per-dst aggregation
    {
        const int l2 = lane * 2;
#pragma unroll 1
        for (int dd = 0; dd < 4; ++dd) {
            const int dl = wv * 4 + dd;
            const int sbase = dl * 8;
            const int e0 = roff_s[sbase];
            const int n = roff_s[sbase + 8] - e0;
            float2 a0 = {0.f, 0.f}, a1 = {0.f, 0.f}, a2 = {0.f, 0.f}, a3 = {0.f, 0.f};
            float2 a4 = {0.f, 0.f}, a5 = {0.f, 0.f}, a6 = {0.f, 0.f}, a7 = {0.f, 0.f};
#pragma unroll 1
            for (int base = 0; base < n; base += 64) {
                int m = min(n - base, 64);
                unsigned ent = 8u << 16;            // sentinel rel=8
                if (lane < m) {
                    int p = e0 + base + lane;
                    int rel = 0;
#pragma unroll
                    for (int r = 1; r < 8; ++r) rel += (p >= roff_s[sbase + r]) ? 1 : 0;
                    ent = (unsigned)csr16[p] | ((unsigned)rel << 16);
                }
                sE32[wv][lane] = ent;
                int mr = (m + 7) & ~7;
#pragma unroll 1
                for (int jb = 0; jb < mr; jb += 8) {
                    unsigned ee[8], vv[8];
#pragma unroll
                    for (int k = 0; k < 8; ++k) ee[k] = sE32[wv][jb + k];
#pragma unroll
                    for (int k = 0; k < 8; ++k)
                        vv[k] = *(const unsigned*)&xb[(ee[k] & 0xFFFFu) * 128 + l2];
#pragma unroll
                    for (int k = 0; k < 8; ++k) {
                        int srel = __builtin_amdgcn_readfirstlane((int)(ee[k] >> 16));
                        float lo = __uint_as_float(vv[k] << 16);
                        float hi = __uint_as_float(vv[k] & 0xFFFF0000u);
                        switch (srel) {
                            case 0: a0.x += lo; a0.y += hi; break;
                            case 1: a1.x += lo; a1.y += hi; break;
                            case 2: a2.x += lo; a2.y += hi; break;
                            case 3: a3.x += lo; a3.y += hi; break;
                            case 4: a4.x += lo; a4.y += hi; break;
                            case 5: a5.x += lo; a5.y += hi; break;
                            case 6: a6.x += lo; a6.y += hi; break;
                            default: break;
                        }
                        if (srel == 7) { a7.x += lo; a7.y += hi; }
                    }
                }
            }
            // pack + store (swizzled, matches phase 2)
            const int mask = (dl & 7) << 4;
            char* rowp = (char*)agg + dl * 2048;
#define PK_STORE(RR, AR)                                                          \
            {                                                                     \
                int len = roff_s[sbase + RR + 1] - roff_s[sbase + RR];            \
                float dv = 1.0f / fmaxf((float)len, 1.0f);                        \
                *(unsigned*)(rowp + (((RR) * 256 + 4 * lane) ^ mask)) =           \
                    cvtpk(AR.x * dv, AR.y * dv);                                  \
            }
            PK_STORE(0, a0) PK_STORE(1, a1) PK_STORE(2, a2) PK_STORE(3, a3)
            PK_STORE(4, a4) PK_STORE(5, a5) PK_STORE(6, a6) PK_STORE(7, a7)
#undef PK_STORE
        }
    }
    __syncthreads();

    // ---- phase 2: wave wv -> cols [wv*16, wv*16+16), rows 0..31 (2 tiles)
    const int lr = lane & 15, lg = lane >> 4;
    const int colb = wv << 4;
    const int mask = (lr & 7) << 4;
    f32x4 acc0 = {0.f, 0.f, 0.f, 0.f}, acc1 = {0.f, 0.f, 0.f, 0.f};
#pragma unroll
    for (int rel = 0; rel < 8; ++rel) {
        const unsigned short* Wp = WbT + rel * 16384 + (colb + lr) * 128;
        const char* rA = (const char*)agg + lr * 2048;
        const char* rB = (const char*)agg + (lr + 16) * 2048;
#pragma unroll
        for (int kk = 0; kk < 4; ++kk) {
            bf16x8 bfr = *(const bf16x8*)&Wp[kk * 32 + lg * 8];
            int kb = (rel * 256 + kk * 64 + lg * 16) ^ mask;
            bf16x8 fa0 = *(const bf16x8*)(rA + kb);
            bf16x8 fa1 = *(const bf16x8*)(rB + kb);
            acc0 = __builtin_amdgcn_mfma_f32_16x16x32_bf16(fa0, bfr, acc0, 0, 0, 0);
            acc1 = __builtin_amdgcn_mfma_f32_16x16x32_bf16(fa1, bfr, acc1, 0, 0, 0);
        }
    }
    {   // self-loop panel: A rows straight from xb
        const unsigned short* Wp = WbT + 8 * 16384 + (colb + lr) * 128;
        int r0 = min(g32 + lr, N_NODES - 1);
        int r1 = min(g32 + 16 + lr, N_NODES - 1);
#pragma unroll
        for (int kk = 0; kk < 4; ++kk) {
            bf16x8 bfr = *(const bf16x8*)&Wp[kk * 32 + lg * 8];
            bf16x8 fa0 = *(const bf16x8*)&xb[(size_t)r0 * 128 + kk * 32 + lg * 8];
            bf16x8 fa1 = *(const bf16x8*)&xb[(size_t)r1 * 128 + kk * 32 + lg * 8];
            acc0 = __builtin_amdgcn_mfma_f32_16x16x32_bf16(fa0, bfr, acc0, 0, 0, 0);
            acc1 = __builtin_amdgcn_mfma_f32_16x16x32_bf16(fa1, bfr, acc1, 0, 0, 0);
        }
    }
#pragma unroll
    for (int q = 0; q < 4; ++q) {
        int row = g32 + lg * 4 + q;
        if (row < N_NODES) out[(size_t)row * 128 + colb + lr] = acc0[q];
    }
#pragma unroll
    for (int q = 0; q < 4; ++q) {
        int row = g32 + 16 + lg * 4 + q;
        if (row < N_NODES) out[(size_t)row * 128 + colb + lr] = acc1[q];
    }
}

// ---------------------------------------------------------------------------
extern "C" void kernel_launch(void* const* d_in, const int* in_sizes, int n_in,
                              void* d_out, int out_size, void* d_ws, size_t ws_size,
                              hipStream_t stream) {
    const float* x         = (const float*)d_in[0];
    const float* bases     = (const float*)d_in[1];
    const float* coeff     = (const float*)d_in[2];
    const float* self_loop = (const float*)d_in[3];
    const int*   ei        = (const int*)d_in[4];
    const int*   et        = (const int*)d_in[5];
    float* out = (float*)d_out;

    char* ws = (char*)d_ws;
    size_t o = 0;
    auto alloc = [&](size_t bytes) { size_t r = o; o += (bytes + 255) & ~(size_t)255; return r; };
    size_t o_ccnt   = alloc(256 * 4);                        // zeroed
    size_t zero_end = o;
    size_t o_coff   = alloc((NCB + 1) * 4);
    size_t o_gcur   = alloc(NCB * 4);
    size_t o_recA   = alloc((size_t)N_EDGES * 4);
    size_t o_csr16  = alloc((size_t)N_EDGES * 2);
    size_t o_roff2  = alloc((size_t)(NSEG + 192) * 4);
    size_t o_WbT    = alloc((size_t)9 * 16384 * 2);
    size_t o_xb     = alloc((size_t)N_NODES * D * 2 + 4096);
    if (ws_size < o) return;

    int*            ccnt  = (int*)(ws + o_ccnt);
    int*            coff  = (int*)(ws + o_coff);
    int*            gcur  = (int*)(ws + o_gcur);
    unsigned int*   recA  = (unsigned int*)(ws + o_recA);
    unsigned short* csr16 = (unsigned short*)(ws + o_csr16);
    int*            roff2 = (int*)(ws + o_roff2);
    unsigned short* WbT   = (unsigned short*)(ws + o_WbT);
    unsigned short* xb    = (unsigned short*)(ws + o_xb);

    hipMemsetAsync(ccnt, 0, zero_end, stream);

    k_setup1<<<K1_HIST + K1_CVT + K1_MKW, 256, 0, stream>>>(x, coeff, bases, self_loop,
                                                            ei, xb, WbT, ccnt);
    k_scanA1<<<1, 256, 0, stream>>>(ccnt, coff, gcur, roff2);
    k_bucketA<<<(N_EDGES + ACHUNK - 1) / ACHUNK, 256, 0, stream>>>(ei, et, gcur, recA);
    k_buildC<<<NCB, 256, 0, stream>>>(recA, coff, roff2, csr16);
    k_fused4<<<NFB, 512, 0, stream>>>(xb, WbT, csr16, roff2, out);
}

// Round 14
// 143.755 us; speedup vs baseline: 1.3523x; 1.3523x over previous
//
#include <hip/hip_runtime.h>
#include <hip/hip_bf16.h>

#define N_NODES 50000
#define N_EDGES 800000
#define N_REL 8
#define N_BASES 16
#define D 128
#define NCB 196   // coarse buckets of 256 dsts
#define ACHUNK 2048

typedef __attribute__((ext_vector_type(8))) short bf16x8;
typedef __attribute__((ext_vector_type(4))) float f32x4;
typedef __attribute__((ext_vector_type(4))) int i32x4;

__device__ inline unsigned short f2bf(float f) {
    unsigned int x = __float_as_uint(f);
    unsigned int r = x + 0x7FFFu + ((x >> 16) & 1u);
    return (unsigned short)(r >> 16);
}

// ---------------------------------------------------------------------------
// K1: fused {histA (blocks 0..781), cvtx (782..3906), makeW (3907..3978)}
#define K1_HIST 782
#define K1_CVT  3125
#define K1_MKW  72
__global__ __launch_bounds__(256) void k_setup1(const float* __restrict__ x,
                                                const float* __restrict__ coeff,
                                                const float* __restrict__ bases,
                                                const float* __restrict__ self_loop,
                                                const int* __restrict__ ei,
                                                unsigned short* __restrict__ xb,
                                                unsigned short* __restrict__ WbT,
                                                int* __restrict__ ccnt) {
    __shared__ int h[256];
    __shared__ unsigned short tile[128][17];
    const int b = blockIdx.x;
    const int t = threadIdx.x;

    if (b < K1_HIST) {
        h[t] = 0;
        __syncthreads();
        int idx = b * 1024 + t * 4;
        if (idx < N_EDGES) {
            int4 d = *(const int4*)&ei[N_EDGES + idx];
            atomicAdd(&h[d.x >> 8], 1);
            atomicAdd(&h[d.y >> 8], 1);
            atomicAdd(&h[d.z >> 8], 1);
            atomicAdd(&h[d.w >> 8], 1);
        }
        __syncthreads();
        if (t < NCB && h[t]) atomicAdd(&ccnt[t], h[t]);
    } else if (b < K1_HIST + K1_CVT) {
        int i = (b - K1_HIST) * 256 + t;
        const float4* xp = (const float4*)x;
        float4 a = xp[i * 2], bb = xp[i * 2 + 1];
        int4 o;
        o.x = (int)f2bf(a.x) | ((int)f2bf(a.y) << 16);
        o.y = (int)f2bf(a.z) | ((int)f2bf(a.w) << 16);
        o.z = (int)f2bf(bb.x) | ((int)f2bf(bb.y) << 16);
        o.w = (int)f2bf(bb.z) | ((int)f2bf(bb.w) << 16);
        ((int4*)xb)[i] = o;
    } else {
        int local = b - K1_HIST - K1_CVT;
        const int r = local >> 3, os = local & 7;
        const int i = t >> 1, ob = (t & 1) * 8;
        const int gcol = os * 16 + ob;
        float s[8];
        if (r < 8) {
            float c[16];
#pragma unroll
            for (int bb = 0; bb < 16; ++bb) c[bb] = coeff[r * 16 + bb];
#pragma unroll
            for (int j = 0; j < 8; ++j) s[j] = 0.f;
#pragma unroll
            for (int bb = 0; bb < 16; ++bb) {
                const float* bp = bases + bb * 16384 + i * 128 + gcol;
                float4 v0 = *(const float4*)bp;
                float4 v1 = *(const float4*)(bp + 4);
                s[0] += c[bb] * v0.x; s[1] += c[bb] * v0.y; s[2] += c[bb] * v0.z; s[3] += c[bb] * v0.w;
                s[4] += c[bb] * v1.x; s[5] += c[bb] * v1.y; s[6] += c[bb] * v1.z; s[7] += c[bb] * v1.w;
            }
        } else {
            const float* sp = self_loop + i * 128 + gcol;
            float4 v0 = *(const float4*)sp;
            float4 v1 = *(const float4*)(sp + 4);
            s[0] = v0.x; s[1] = v0.y; s[2] = v0.z; s[3] = v0.w;
            s[4] = v1.x; s[5] = v1.y; s[6] = v1.z; s[7] = v1.w;
        }
#pragma unroll
        for (int j = 0; j < 8; ++j) tile[i][ob + j] = f2bf(s[j]);
        __syncthreads();
        const int o = t >> 4, ic = (t & 15) << 3;
        unsigned int pk[4];
#pragma unroll
        for (int j = 0; j < 4; ++j)
            pk[j] = (unsigned int)tile[ic + j * 2][o] | ((unsigned int)tile[ic + j * 2 + 1][o] << 16);
        *(int4*)&WbT[(size_t)r * 16384 + (os * 16 + o) * 128 + ic] = *(int4*)pk;
    }
}

// ---------------------------------------------------------------------------
// exclusive scan of ccnt[196] -> coff[197], gcur; row_off[N] = total
__global__ __launch_bounds__(256) void k_scanA1(const int* __restrict__ ccnt,
                                                int* __restrict__ coff,
                                                int* __restrict__ gcur,
                                                int* __restrict__ row_off) {
    int t = threadIdx.x;
    int v = (t < NCB) ? ccnt[t] : 0;
    int lane = t & 63, wv = t >> 6;
    int inc = v;
#pragma unroll
    for (int off = 1; off < 64; off <<= 1) {
        int y = __shfl_up(inc, off);
        if (lane >= off) inc += y;
    }
    __shared__ int ws4[4];
    if (lane == 63) ws4[wv] = inc;
    __syncthreads();
    int wb = 0;
    for (int i = 0; i < wv; ++i) wb += ws4[i];
    int ex = wb + inc - v;
    if (t < NCB) { coff[t] = ex; gcur[t] = ex; }
    if (t == NCB - 1) { coff[NCB] = ex + v; row_off[N_NODES] = ex + v; }
}

// ---------------------------------------------------------------------------
// K3: fused {bucketA (blocks 0..390, dispatched first), mm9 (391..3918)}.
// mm9: XCD-swizzled (all 9 panels of a row-tile on one XCD -> As L2 reuse);
// B-fragments straight from L2-resident WbT (no Bs staging) -> 36 KB LDS ->
// 4 blocks/CU; epilogue stages xW tile through As, nontemporal dwordx4 out.
__global__ __launch_bounds__(512) void k_work(const int* __restrict__ ei,
                                              const int* __restrict__ et,
                                              int* __restrict__ gcur,
                                              unsigned int* __restrict__ recA,
                                              const unsigned short* __restrict__ xb,
                                              const unsigned short* __restrict__ WbT,
                                              unsigned short* __restrict__ xW,
                                              float* __restrict__ out, int M) {
    __shared__ unsigned short As[128][136];
    __shared__ int lcnt[NCB], lbase[NCB];
    const int bid = blockIdx.x;
    const int t = threadIdx.x;

    if (bid < 391) {
        // ---- bucketA: 2048 edges, 512 threads x 4
        const int base = bid * ACHUNK;
        if (t < NCB) lcnt[t] = 0;
        __syncthreads();
        unsigned int rec[4];
        int mb[4];
#pragma unroll
        for (int i = 0; i < 4; ++i) {
            int e = base + t + i * 512;
            if (e < N_EDGES) {
                int src = ei[e];
                int dst = ei[N_EDGES + e];
                int r = et[e];
                rec[i] = (unsigned)src | ((unsigned)r << 16) | ((unsigned)(dst & 255) << 19);
                mb[i] = dst >> 8;
                atomicAdd(&lcnt[mb[i]], 1);
            } else mb[i] = -1;
        }
        __syncthreads();
        if (t < NCB) lbase[t] = lcnt[t] ? atomicAdd(&gcur[t], lcnt[t]) : 0;
        __syncthreads();
        if (t < NCB) lcnt[t] = 0;
        __syncthreads();
#pragma unroll
        for (int i = 0; i < 4; ++i) {
            if (mb[i] < 0) continue;
            int pos = lbase[mb[i]] + atomicAdd(&lcnt[mb[i]], 1);
            recA[pos] = rec[i];
        }
        return;
    }

    // ---- mm9, XCD-swizzled
    const int local = bid - 391;            // 0..3527
    const int c = (local + 7) & 7;
    const int slot = local >> 3;            // 0..440
    const int tile = c * 49 + slot / 9;
    const int p = slot % 9;
    if (tile >= 391) return;
    const int rb = tile * 128;
    const unsigned short* Wp = WbT + p * 16384;

#pragma unroll
    for (int i = 0; i < 4; ++i) {
        int f = t + i * 512;
        int row = f >> 4, c8 = (f & 15) << 3;
        int gr = rb + row;
        int4 v = make_int4(0, 0, 0, 0);
        if (gr < M) v = *(const int4*)&xb[(size_t)gr * D + c8];
        *(int4*)&As[row][c8] = v;
    }
    __syncthreads();

    const int w = t >> 6, lane = t & 63;
    const int rh = (w >> 2) * 64, cq = (w & 3) * 32;
    const int lr = lane & 15, lg = lane >> 4;

    f32x4 acc[4][2] = {};
#pragma unroll
    for (int kk = 0; kk < 4; ++kk) {
        int ko = kk * 32 + lg * 8;
        bf16x8 a[4], b[2];
#pragma unroll
        for (int n = 0; n < 2; ++n) b[n] = *(const bf16x8*)&Wp[(cq + n * 16 + lr) * 128 + ko];
#pragma unroll
        for (int m = 0; m < 4; ++m) a[m] = *(const bf16x8*)&As[rh + m * 16 + lr][ko];
#pragma unroll
        for (int m = 0; m < 4; ++m)
#pragma unroll
            for (int n = 0; n < 2; ++n)
                acc[m][n] = __builtin_amdgcn_mfma_f32_16x16x32_bf16(a[m], b[n], acc[m][n], 0, 0, 0);
    }

    if (p < 8) {
        __syncthreads();   // all waves done reading As
#pragma unroll
        for (int m = 0; m < 4; ++m)
#pragma unroll
            for (int n = 0; n < 2; ++n)
#pragma unroll
                for (int q = 0; q < 4; ++q)
                    As[rh + m * 16 + lg * 4 + q][cq + n * 16 + lr] = f2bf(acc[m][n][q]);
        __syncthreads();
#pragma unroll
        for (int i = 0; i < 4; ++i) {
            int f = t + i * 512;
            int row = f >> 4, c8 = (f & 15) << 3;
            int gr = rb + row;
            if (gr < M) {
                i32x4 v = *(const i32x4*)&As[row][c8];
                __builtin_nontemporal_store(v, (i32x4*)&xW[(size_t)gr * 1024 + p * 128 + c8]);
            }
        }
    } else {
#pragma unroll
        for (int m = 0; m < 4; ++m)
#pragma unroll
            for (int n = 0; n < 2; ++n)
#pragma unroll
                for (int q = 0; q < 4; ++q) {
                    int grow = rb + rh + m * 16 + lg * 4 + q;
                    int col = cq + n * 16 + lr;
                    if (grow < M) out[(size_t)grow * 128 + col] = acc[m][n][q];
                }
    }
}

// ---------------------------------------------------------------------------
// per coarse bucket: dst-sorted csr + row_off + dinv (all LDS atomics)
__global__ __launch_bounds__(256) void k_buildC(const unsigned int* __restrict__ recA,
                                                const int* __restrict__ coff,
                                                int* __restrict__ row_off,
                                                int* __restrict__ csr,
                                                float* __restrict__ dinv) {
    const int b = blockIdx.x, t = threadIdx.x;
    const int s0 = coff[b], s1 = coff[b + 1];
    __shared__ int h2[2048];   // (dst&255)*8 + rel
    __shared__ int cur[256];
    __shared__ int ws4[4];
    for (int i = t; i < 2048; i += 256) h2[i] = 0;
    __syncthreads();
    for (int i = s0 + t; i < s1; i += 256) {
        unsigned int p = recA[i];
        atomicAdd(&h2[((p >> 19) & 255) * 8 + ((p >> 16) & 7)], 1);
    }
    __syncthreads();
    int sum = 0;
#pragma unroll
    for (int r = 0; r < 8; ++r) sum += h2[t * 8 + r];
    int lane = t & 63, wv = t >> 6;
    int inc = sum;
#pragma unroll
    for (int off = 1; off < 64; off <<= 1) {
        int y = __shfl_up(inc, off);
        if (lane >= off) inc += y;
    }
    if (lane == 63) ws4[wv] = inc;
    __syncthreads();
    int wb = 0;
    for (int i = 0; i < wv; ++i) wb += ws4[i];
    int ex = wb + inc - sum;
    cur[t] = ex;
    int dst = (b << 8) + t;
    if (dst < N_NODES) row_off[dst] = s0 + ex;
    __syncthreads();
    for (int i = t; i < 2048; i += 256) {
        int d2 = (b << 8) + (i >> 3);
        if (d2 < N_NODES) dinv[(size_t)d2 * 8 + (i & 7)] = 1.0f / fmaxf((float)h2[i], 1.0f);
    }
    for (int i = s0 + t; i < s1; i += 256) {
        unsigned int p = recA[i];
        int pos = s0 + atomicAdd(&cur[(p >> 19) & 255], 1);
        csr[pos] = (int)(p & 0x7FFFF);   // src | rel<<16
    }
}

// ---------------------------------------------------------------------------
// wave-per-dst gather: 64 lanes cover the 256B xW row, edges staged in LDS,
// 16-deep unrolled loads for MLP, float2 RMW out.
__global__ __launch_bounds__(256) void k_gather2(const unsigned short* __restrict__ xW,
                                                 const int* __restrict__ csr,
                                                 const int* __restrict__ row_off,
                                                 const float* __restrict__ dinv,
                                                 float* __restrict__ out) {
    __shared__ int eL[4][64];
    __shared__ float dv[4][16];
    const int t = threadIdx.x;
    const int wv = t >> 6, lane = t & 63;
    const int dst = blockIdx.x * 4 + wv;          // grid 12500 exact
    const int s0 = row_off[dst], s1 = row_off[dst + 1];
    const int n = s1 - s0;
    if (lane < 8) dv[wv][lane] = dinv[(size_t)dst * 8 + lane];
    else if (lane < 16) dv[wv][lane] = 0.f;       // sentinel scale (rel>=8)
    if (n <= 0) return;                           // wave-uniform
    float a0 = 0.f, a1 = 0.f;
    const int loff = lane * 2;
    for (int base = 0; base < n; base += 64) {
        int m = min(n - base, 64);
        int e = (lane < m) ? csr[s0 + base + lane] : (8 << 16);
        eL[wv][lane] = e;
        int mr = (m + 15) & ~15;
        for (int jb = 0; jb < mr; jb += 16) {
            float sc[16];
            unsigned vv[16];
#pragma unroll
            for (int k = 0; k < 16; ++k) {
                int ee = eL[wv][jb + k];
                int src = ee & 0xFFFF;
                int rl = (ee >> 16) & 15;
                sc[k] = dv[wv][rl];
                vv[k] = *(const unsigned*)&xW[(size_t)src * 1024 + rl * 128 + loff];
            }
#pragma unroll
            for (int k = 0; k < 16; ++k) {
                a0 += sc[k] * __uint_as_float(vv[k] << 16);
                a1 += sc[k] * __uint_as_float(vv[k] & 0xFFFF0000u);
            }
        }
    }
    float2* op = (float2*)&out[(size_t)dst * 128 + loff];
    float2 cur = *op;
    cur.x += a0;
    cur.y += a1;
    *op = cur;
}

// ---------------------------------------------------------------------------
extern "C" void kernel_launch(void* const* d_in, const int* in_sizes, int n_in,
                              void* d_out, int out_size, void* d_ws, size_t ws_size,
                              hipStream_t stream) {
    const float* x         = (const float*)d_in[0];
    const float* bases     = (const float*)d_in[1];
    const float* coeff     = (const float*)d_in[2];
    const float* self_loop = (const float*)d_in[3];
    const int*   ei        = (const int*)d_in[4];
    const int*   et        = (const int*)d_in[5];
    float* out = (float*)d_out;

    char* ws = (char*)d_ws;
    size_t o = 0;
    auto alloc = [&](size_t bytes) { size_t r = o; o += (bytes + 255) & ~(size_t)255; return r; };
    size_t o_ccnt   = alloc(256 * 4);                        // zeroed
    size_t zero_end = o;
    size_t o_coff   = alloc((NCB + 1) * 4);
    size_t o_gcur   = alloc(NCB * 4);
    size_t o_rowoff = alloc((size_t)(N_NODES + 1) * 4);
    size_t o_recA   = alloc((size_t)N_EDGES * 4);
    size_t o_csr    = alloc((size_t)N_EDGES * 4);
    size_t o_dinv   = alloc((size_t)N_NODES * 8 * 4);
    size_t o_WbT    = alloc((size_t)9 * 16384 * 2);
    size_t o_xb     = alloc((size_t)N_NODES * D * 2);
    size_t o_xW     = alloc((size_t)N_NODES * 1024 * 2 + 4096);
    if (ws_size < o) return;

    int*            ccnt    = (int*)(ws + o_ccnt);
    int*            coff    = (int*)(ws + o_coff);
    int*            gcur    = (int*)(ws + o_gcur);
    int*            row_off = (int*)(ws + o_rowoff);
    unsigned int*   recA    = (unsigned int*)(ws + o_recA);
    int*            csr     = (int*)(ws + o_csr);
    float*          dinv    = (float*)(ws + o_dinv);
    unsigned short* WbT     = (unsigned short*)(ws + o_WbT);
    unsigned short* xb      = (unsigned short*)(ws + o_xb);
    unsigned short* xW      = (unsigned short*)(ws + o_xW);

    hipMemsetAsync(ccnt, 0, zero_end, stream);

    k_setup1<<<K1_HIST + K1_CVT + K1_MKW, 256, 0, stream>>>(x, coeff, bases, self_loop,
                                                            ei, xb, WbT, ccnt);
    k_scanA1<<<1, 256, 0, stream>>>(ccnt, coff, gcur, row_off);
    k_work<<<391 + 3528, 512, 0, stream>>>(ei, et, gcur, recA, xb, WbT, xW, out, N_NODES);
    k_buildC<<<NCB, 256, 0, stream>>>(recA, coff, row_off, csr, dinv);
    k_gather2<<<12500, 256, 0, stream>>>(xW, csr, row_off, dinv, out);
}

// Round 15
// 103.226 us; speedup vs baseline: 1.8832x; 1.3926x over previous
//
#include <hip/hip_runtime.h>
#include <hip/hip_bf16.h>

#define N_NODES 50000
#define N_EDGES 800000
#define N_REL 8
#define N_BASES 16
#define D 128
#define NCB 196     // coarse buckets of 256 dsts
#define CAP 5120    // fixed bucket capacity (mean 4096, sigma 64)
#define ACHUNK 2048

typedef __attribute__((ext_vector_type(8))) short bf16x8;
typedef __attribute__((ext_vector_type(4))) float f32x4;

__device__ inline unsigned short f2bf(float f) {
    unsigned int x = __float_as_uint(f);
    unsigned int r = x + 0x7FFFu + ((x >> 16) & 1u);
    return (unsigned short)(r >> 16);
}

// ---------------------------------------------------------------------------
// D1: fused {bucketA (0..390), cvtx (391..3515), makeW (3516..3587)}
#define S_BUK 391
#define S_CVT 3125
#define S_MKW 72
__global__ __launch_bounds__(256) void k_setupA(const float* __restrict__ x,
                                                const float* __restrict__ coeff,
                                                const float* __restrict__ bases,
                                                const float* __restrict__ self_loop,
                                                const int* __restrict__ ei,
                                                const int* __restrict__ et,
                                                unsigned short* __restrict__ xb,
                                                unsigned short* __restrict__ WbT,
                                                int* __restrict__ cnt,
                                                unsigned int* __restrict__ recA) {
    __shared__ int lcnt[NCB], lbase[NCB];
    __shared__ unsigned short tile[128][17];
    const int b = blockIdx.x;
    const int t = threadIdx.x;

    if (b < S_BUK) {
        // ---- bucketA: 2048 edges, fixed-capacity buckets
        const int base = b * ACHUNK;
        if (t < NCB) lcnt[t] = 0;
        __syncthreads();
        unsigned int rec[8];
        int mb[8];
#pragma unroll
        for (int i = 0; i < 8; ++i) {
            int e = base + t + i * 256;
            if (e < N_EDGES) {
                int src = ei[e];
                int dst = ei[N_EDGES + e];
                int r = et[e];
                rec[i] = (unsigned)src | ((unsigned)r << 16) | ((unsigned)(dst & 255) << 19);
                mb[i] = dst >> 8;
                atomicAdd(&lcnt[mb[i]], 1);
            } else mb[i] = -1;
        }
        __syncthreads();
        if (t < NCB) lbase[t] = lcnt[t] ? atomicAdd(&cnt[t], lcnt[t]) : 0;
        __syncthreads();
        if (t < NCB) lcnt[t] = 0;
        __syncthreads();
#pragma unroll
        for (int i = 0; i < 8; ++i) {
            if (mb[i] < 0) continue;
            int pos = lbase[mb[i]] + atomicAdd(&lcnt[mb[i]], 1);
            recA[mb[i] * CAP + pos] = rec[i];
        }
    } else if (b < S_BUK + S_CVT) {
        // ---- xb = bf16(x)
        int i = (b - S_BUK) * 256 + t;
        const float4* xp = (const float4*)x;
        float4 a = xp[i * 2], bb = xp[i * 2 + 1];
        int4 o;
        o.x = (int)f2bf(a.x) | ((int)f2bf(a.y) << 16);
        o.y = (int)f2bf(a.z) | ((int)f2bf(a.w) << 16);
        o.z = (int)f2bf(bb.x) | ((int)f2bf(bb.y) << 16);
        o.w = (int)f2bf(bb.z) | ((int)f2bf(bb.w) << 16);
        ((int4*)xb)[i] = o;
    } else {
        // ---- WbT[r][o][i]
        int local = b - S_BUK - S_CVT;
        const int r = local >> 3, os = local & 7;
        const int i = t >> 1, ob = (t & 1) * 8;
        const int gcol = os * 16 + ob;
        float s[8];
        if (r < 8) {
            float c[16];
#pragma unroll
            for (int bb = 0; bb < 16; ++bb) c[bb] = coeff[r * 16 + bb];
#pragma unroll
            for (int j = 0; j < 8; ++j) s[j] = 0.f;
#pragma unroll
            for (int bb = 0; bb < 16; ++bb) {
                const float* bp = bases + bb * 16384 + i * 128 + gcol;
                float4 v0 = *(const float4*)bp;
                float4 v1 = *(const float4*)(bp + 4);
                s[0] += c[bb] * v0.x; s[1] += c[bb] * v0.y; s[2] += c[bb] * v0.z; s[3] += c[bb] * v0.w;
                s[4] += c[bb] * v1.x; s[5] += c[bb] * v1.y; s[6] += c[bb] * v1.z; s[7] += c[bb] * v1.w;
            }
        } else {
            const float* sp = self_loop + i * 128 + gcol;
            float4 v0 = *(const float4*)sp;
            float4 v1 = *(const float4*)(sp + 4);
            s[0] = v0.x; s[1] = v0.y; s[2] = v0.z; s[3] = v0.w;
            s[4] = v1.x; s[5] = v1.y; s[6] = v1.z; s[7] = v1.w;
        }
#pragma unroll
        for (int j = 0; j < 8; ++j) tile[i][ob + j] = f2bf(s[j]);
        __syncthreads();
        const int o = t >> 4, ic = (t & 15) << 3;
        unsigned int pk[4];
#pragma unroll
        for (int j = 0; j < 4; ++j)
            pk[j] = (unsigned int)tile[ic + j * 2][o] | ((unsigned int)tile[ic + j * 2 + 1][o] << 16);
        *(int4*)&WbT[(size_t)r * 16384 + (os * 16 + o) * 128 + ic] = *(int4*)pk;
    }
}

// ---------------------------------------------------------------------------
// D2: fused {buildC (blocks 0..195, first), mm9 (196..3723, XCD-swizzled)}.
// buildC LDS aliases onto As/Bs so LDS stays ~70KB (2 blocks/CU for mm9).
__global__ __launch_bounds__(512) void k_workB(const unsigned int* __restrict__ recA,
                                               const int* __restrict__ cnt,
                                               unsigned int* __restrict__ rowpk,
                                               int* __restrict__ csr,
                                               float* __restrict__ dinv,
                                               const unsigned short* __restrict__ xb,
                                               const unsigned short* __restrict__ WbT,
                                               unsigned short* __restrict__ xW,
                                               float* __restrict__ out, int M) {
    __shared__ __attribute__((aligned(16))) unsigned short As[128][136];
    __shared__ __attribute__((aligned(16))) unsigned short Bs[128][136];
    __shared__ int ws8[8];
    const int bid = blockIdx.x;
    const int t = threadIdx.x;

    if (bid < NCB) {
        // ---- buildC (512 threads), LDS aliased onto As/Bs
        int* h2   = (int*)&As[0][0];    // 2048 ints
        int* cur2 = (int*)&Bs[0][0];    // 2049 ints
        const int b = bid;
        const int base = b * CAP;
        const int cb = cnt[b];
        for (int i = t; i < 2048; i += 512) h2[i] = 0;
        __syncthreads();
        for (int i = t; i < cb; i += 512) {
            unsigned int p = recA[base + i];
            atomicAdd(&h2[((p >> 19) & 255) * 8 + ((p >> 16) & 7)], 1);
        }
        __syncthreads();
        int pre[4], sum = 0;
#pragma unroll
        for (int j = 0; j < 4; ++j) { pre[j] = sum; sum += h2[t * 4 + j]; }
        int lane = t & 63, wv = t >> 6;
        int inc = sum;
#pragma unroll
        for (int off = 1; off < 64; off <<= 1) {
            int y = __shfl_up(inc, off);
            if (lane >= off) inc += y;
        }
        if (lane == 63) ws8[wv] = inc;
        __syncthreads();
        int wb = 0;
        for (int i = 0; i < wv; ++i) wb += ws8[i];
        int ex = wb + inc - sum;
#pragma unroll
        for (int j = 0; j < 4; ++j) cur2[t * 4 + j] = ex + pre[j];
        if (t == 0) {
            int tot = 0;
#pragma unroll
            for (int i = 0; i < 8; ++i) tot += ws8[i];
            cur2[2048] = tot;
        }
        __syncthreads();
        if (t < 256) {
            int dst = (b << 8) + t;
            if (dst < N_NODES) {
                int s = cur2[t * 8], e2 = cur2[t * 8 + 8];
                rowpk[dst] = (unsigned)(base + s) | ((unsigned)(e2 - s) << 21);
            }
        }
        for (int i = t; i < 2048; i += 512) {
            int d2 = (b << 8) + (i >> 3);
            if (d2 < N_NODES) dinv[(size_t)d2 * 8 + (i & 7)] = 1.0f / fmaxf((float)h2[i], 1.0f);
        }
        __syncthreads();
        for (int i = t; i < cb; i += 512) {
            unsigned int p = recA[base + i];
            int idx2 = ((p >> 19) & 255) * 8 + ((p >> 16) & 7);
            int pos = base + atomicAdd(&cur2[idx2], 1);
            csr[pos] = (int)(p & 0x7FFFF);   // src | rel<<16
        }
        return;
    }

    // ---- mm9, XCD-swizzled (offset by NCB=196 preceding blocks: 196%8=4)
    const int local = bid - NCB;            // 0..3527
    const int c = (local + 4) & 7;          // presumed XCD of this block
    const int slot = local >> 3;            // 0..440
    const int tile = c * 49 + slot / 9;
    const int p = slot % 9;
    if (tile >= 391) return;
    const int rb = tile * 128;
    const unsigned short* Bsrc = WbT + p * 16384;

#pragma unroll
    for (int i = 0; i < 4; ++i) {
        int f = t + i * 512;
        int row = f >> 4, c8 = (f & 15) << 3;
        int gr = rb + row;
        int4 v = make_int4(0, 0, 0, 0);
        if (gr < M) v = *(const int4*)&xb[(size_t)gr * D + c8];
        *(int4*)&As[row][c8] = v;
        *(int4*)&Bs[row][c8] = *(const int4*)&Bsrc[row * 128 + c8];
    }
    __syncthreads();

    const int w = t >> 6, lane = t & 63;
    const int rh = (w >> 2) * 64, cq = (w & 3) * 32;
    const int lr = lane & 15, lg = lane >> 4;

    f32x4 acc[4][2] = {};
#pragma unroll
    for (int kk = 0; kk < 4; ++kk) {
        int ko = kk * 32 + lg * 8;
        bf16x8 a[4], b[2];
#pragma unroll
        for (int m = 0; m < 4; ++m) a[m] = *(const bf16x8*)&As[rh + m * 16 + lr][ko];
#pragma unroll
        for (int n = 0; n < 2; ++n) b[n] = *(const bf16x8*)&Bs[cq + n * 16 + lr][ko];
#pragma unroll
        for (int m = 0; m < 4; ++m)
#pragma unroll
            for (int n = 0; n < 2; ++n)
                acc[m][n] = __builtin_amdgcn_mfma_f32_16x16x32_bf16(a[m], b[n], acc[m][n], 0, 0, 0);
    }

    if (p < 8) {
        __syncthreads();   // all waves done reading Bs
#pragma unroll
        for (int m = 0; m < 4; ++m)
#pragma unroll
            for (int n = 0; n < 2; ++n)
#pragma unroll
                for (int q = 0; q < 4; ++q)
                    Bs[rh + m * 16 + lg * 4 + q][cq + n * 16 + lr] = f2bf(acc[m][n][q]);
        __syncthreads();
#pragma unroll
        for (int i = 0; i < 4; ++i) {
            int f = t + i * 512;
            int row = f >> 4, c8 = (f & 15) << 3;
            int gr = rb + row;
            if (gr < M) *(int4*)&xW[(size_t)gr * 1024 + p * 128 + c8] = *(const int4*)&Bs[row][c8];
        }
    } else {
#pragma unroll
        for (int m = 0; m < 4; ++m)
#pragma unroll
            for (int n = 0; n < 2; ++n)
#pragma unroll
                for (int q = 0; q < 4; ++q) {
                    int grow = rb + rh + m * 16 + lg * 4 + q;
                    int col = cq + n * 16 + lr;
                    if (grow < M) out[(size_t)grow * 128 + col] = acc[m][n][q];
                }
    }
}

// ---------------------------------------------------------------------------
// wave-per-dst gather: 64 lanes cover the 256B xW row, edges staged in LDS,
// 16-deep unrolled loads for MLP, float2 RMW out. rowpk = start | count<<21.
__global__ __launch_bounds__(256) void k_gather2(const unsigned short* __restrict__ xW,
                                                 const int* __restrict__ csr,
                                                 const unsigned int* __restrict__ rowpk,
                                                 const float* __restrict__ dinv,
                                                 float* __restrict__ out) {
    __shared__ int eL[4][64];
    __shared__ float dv[4][16];
    const int t = threadIdx.x;
    const int wv = t >> 6, lane = t & 63;
    const int dst = blockIdx.x * 4 + wv;          // grid 12500 exact
    const unsigned pk = rowpk[dst];
    const int s0 = (int)(pk & 0x1FFFFF);
    const int n = (int)(pk >> 21);
    if (lane < 8) dv[wv][lane] = dinv[(size_t)dst * 8 + lane];
    else if (lane < 16) dv[wv][lane] = 0.f;       // sentinel scale (rel>=8)
    if (n <= 0) return;                           // wave-uniform
    float a0 = 0.f, a1 = 0.f;
    const int loff = lane * 2;
    for (int base = 0; base < n; base += 64) {
        int m = min(n - base, 64);
        int e = (lane < m) ? csr[s0 + base + lane] : (8 << 16);
        eL[wv][lane] = e;
        int mr = (m + 15) & ~15;
        for (int jb = 0; jb < mr; jb += 16) {
            float sc[16];
            unsigned vv[16];
#pragma unroll
            for (int k = 0; k < 16; ++k) {
                int ee = eL[wv][jb + k];
                int src = ee & 0xFFFF;
                int rl = (ee >> 16) & 15;
                sc[k] = dv[wv][rl];
                vv[k] = *(const unsigned*)&xW[(size_t)src * 1024 + rl * 128 + loff];
            }
#pragma unroll
            for (int k = 0; k < 16; ++k) {
                a0 += sc[k] * __uint_as_float(vv[k] << 16);
                a1 += sc[k] * __uint_as_float(vv[k] & 0xFFFF0000u);
            }
        }
    }
    float2* op = (float2*)&out[(size_t)dst * 128 + loff];
    float2 cur = *op;
    cur.x += a0;
    cur.y += a1;
    *op = cur;
}

// ---------------------------------------------------------------------------
extern "C" void kernel_launch(void* const* d_in, const int* in_sizes, int n_in,
                              void* d_out, int out_size, void* d_ws, size_t ws_size,
                              hipStream_t stream) {
    const float* x         = (const float*)d_in[0];
    const float* bases     = (const float*)d_in[1];
    const float* coeff     = (const float*)d_in[2];
    const float* self_loop = (const float*)d_in[3];
    const int*   ei        = (const int*)d_in[4];
    const int*   et        = (const int*)d_in[5];
    float* out = (float*)d_out;

    char* ws = (char*)d_ws;
    size_t o = 0;
    auto alloc = [&](size_t bytes) { size_t r = o; o += (bytes + 255) & ~(size_t)255; return r; };
    size_t o_cnt   = alloc(1024);                            // zeroed
    size_t zero_end = o;
    size_t o_recA  = alloc((size_t)NCB * CAP * 4);           // 4.0 MB
    size_t o_csr   = alloc((size_t)NCB * CAP * 4);           // 4.0 MB
    size_t o_dinv  = alloc((size_t)N_NODES * 8 * 4);
    size_t o_rowpk = alloc((size_t)N_NODES * 4);
    size_t o_WbT   = alloc((size_t)9 * 16384 * 2);
    size_t o_xb    = alloc((size_t)N_NODES * D * 2);
    size_t o_xW    = alloc((size_t)N_NODES * 1024 * 2 + 4096);
    if (ws_size < o) return;

    int*            cnt   = (int*)(ws + o_cnt);
    unsigned int*   recA  = (unsigned int*)(ws + o_recA);
    int*            csr   = (int*)(ws + o_csr);
    float*          dinv  = (float*)(ws + o_dinv);
    unsigned int*   rowpk = (unsigned int*)(ws + o_rowpk);
    unsigned short* WbT   = (unsigned short*)(ws + o_WbT);
    unsigned short* xb    = (unsigned short*)(ws + o_xb);
    unsigned short* xW    = (unsigned short*)(ws + o_xW);

    hipMemsetAsync(cnt, 0, zero_end, stream);

    k_setupA<<<S_BUK + S_CVT + S_MKW, 256, 0, stream>>>(x, coeff, bases, self_loop,
                                                        ei, et, xb, WbT, cnt, recA);
    k_workB<<<NCB + 3528, 512, 0, stream>>>(recA, cnt, rowpk, csr, dinv,
                                            xb, WbT, xW, out, N_NODES);
    k_gather2<<<12500, 256, 0, stream>>>(xW, csr, rowpk, dinv, out);
}